// Round 7
// baseline (356.768 us; speedup 1.0000x reference)
//
#include <hip/hip_runtime.h>
#include <stdint.h>

typedef unsigned short u16;
typedef unsigned int u32;
typedef __bf16 bf16x8 __attribute__((ext_vector_type(8)));
typedef float f32x4 __attribute__((ext_vector_type(4)));

#define NH 12
#define HD 64
#define SEQ 512
#define BATCH 16
#define HID 768
#define SCALE_Q 0.03608439182435161f  // 768^-0.5

__device__ __forceinline__ u16 f2bf(float f) {
    u32 u = __builtin_bit_cast(u32, f);
    u32 r = (u + 0x7FFFu + ((u >> 16) & 1u)) >> 16;
    return (u16)r;
}
__device__ __forceinline__ float bf2f(u16 h) {
    return __builtin_bit_cast(float, (u32)h << 16);
}

// ---------------- fused fp32 -> bf16 convert (all 6 tensors, one launch) ----------------
#define NXB 6144   // NX/1024
#define NEB 4096   // NE/1024
#define NWB 576    // NW/1024
__global__ void cvt_all(const float* __restrict__ x, const float* __restrict__ eb,
                        const float* __restrict__ w0, const float* __restrict__ w1,
                        const float* __restrict__ w2, const float* __restrict__ w3,
                        u16* __restrict__ dst) {
    int b = blockIdx.x;
    const float* s; int sb;
    if (b < NXB) { s = x; sb = 0; }
    else if (b < NXB + NEB) { s = eb; sb = NXB; }
    else if (b < NXB + NEB + NWB) { s = w0; sb = NXB + NEB; }
    else if (b < NXB + NEB + 2 * NWB) { s = w1; sb = NXB + NEB + NWB; }
    else if (b < NXB + NEB + 3 * NWB) { s = w2; sb = NXB + NEB + 2 * NWB; }
    else { s = w3; sb = NXB + NEB + 3 * NWB; }
    int li = (b - sb) * 1024 + threadIdx.x * 4;
    float4 v = *(const float4*)(s + li);
    ushort4 o;
    o.x = f2bf(v.x); o.y = f2bf(v.y); o.z = f2bf(v.z); o.w = f2bf(v.w);
    *(ushort4*)(dst + (size_t)b * 1024 + threadIdx.x * 4) = o;
}

// ---------------- barrier-free NT GEMM mainloop: direct global->VGPR fragments ----------------
// Every fragment is a contiguous 16B global load (NT layout). No LDS, no
// __syncthreads, no vmcnt(0) drain: loads are software-pipelined 1 K-iter
// ahead; compiler emits fine-grained vmcnt(N) interleaved with MFMA.
__device__ __forceinline__ void load_frags(
    const u16* __restrict__ A0, const u16* __restrict__ B0, int koff,
    bf16x8 (&af)[4], bf16x8 (&bfr)[4])
{
#pragma unroll
    for (int mi = 0; mi < 4; mi++)
        af[mi] = *(const bf16x8*)(A0 + (size_t)mi * 16 * HID + koff);
#pragma unroll
    for (int ni = 0; ni < 4; ni++)
        bfr[ni] = *(const bf16x8*)(B0 + (size_t)ni * 16 * HID + koff);
}

__device__ __forceinline__ void gemm_mainloop(
    const u16* __restrict__ Ag, const u16* __restrict__ Bg, f32x4 (&acc)[4][4])
{
    const int tid = threadIdx.x;
    const int l = tid & 63, w = tid >> 6;
    const int wm = w & 1, wn = w >> 1;
    const int lr = l & 15, lg = l >> 4;

    const u16* A0 = Ag + (size_t)(wm * 64 + lr) * HID + lg * 8;
    const u16* B0 = Bg + (size_t)(wn * 64 + lr) * HID + lg * 8;

    bf16x8 af[4], bfr[4], afn[4], bfn[4];
    load_frags(A0, B0, 0, af, bfr);

    for (int i = 0; i < 24; i++) {
        if (i < 23)
            load_frags(A0, B0, (i + 1) * 32, afn, bfn);
#pragma unroll
        for (int mi = 0; mi < 4; mi++)
#pragma unroll
            for (int ni = 0; ni < 4; ni++)
                acc[mi][ni] = __builtin_amdgcn_mfma_f32_16x16x32_bf16(af[mi], bfr[ni], acc[mi][ni], 0, 0, 0);
#pragma unroll
        for (int j = 0; j < 4; j++) { af[j] = afn[j]; bfr[j] = bfn[j]; }
    }
}

// ---------------- fused QKV GEMM (R5 grid/epilogue) ----------------
__global__ __launch_bounds__(256, 3) void gemm_qkv(
    const u16* __restrict__ xb, const u16* __restrict__ wq,
    const u16* __restrict__ wk, const u16* __restrict__ wv,
    const float* __restrict__ bv,
    u16* __restrict__ qtb, u16* __restrict__ kb, u16* __restrict__ vtb)
{
    const int tid = threadIdx.x;
    const int l = tid & 63, w = tid >> 6;
    const int wm = w & 1, wn = w >> 1;
    const int lr = l & 15, lg = l >> 4;
    const int mt = blockIdx.x, nt = blockIdx.y, z = blockIdx.z;

    const u16* Bw = (z == 0) ? wq : (z == 1) ? wk : wv;
    const u16* Ag = xb + (size_t)(mt * 128) * HID;
    const u16* Bg = Bw + (size_t)(nt * 128) * HID;

    f32x4 acc[4][4] = {};
    gemm_mainloop(Ag, Bg, acc);

    const float sc = (z == 0) ? SCALE_Q : 1.0f;
#pragma unroll
    for (int mi = 0; mi < 4; mi++) {
#pragma unroll
        for (int ni = 0; ni < 4; ni++) {
            const int jg = nt * 128 + wn * 64 + ni * 16 + lr;
            const int h = jg >> 6, d = jg & 63;
            const int i0 = mt * 128 + wm * 64 + mi * 16 + lg * 4;
            const int b = i0 >> 9, n0 = i0 & 511;
            if (z == 1) {  // K: [b,h,m,d]
#pragma unroll
                for (int r2 = 0; r2 < 4; r2++)
                    kb[((size_t)(b * NH + h) * SEQ + n0 + r2) * HD + d] = f2bf(acc[mi][ni][r2]);
            } else {       // Q/V: [b,h,d,n] packed along n
                float bb = (z == 2) ? bv[jg] : 0.0f;
                ushort4 pk;
                pk.x = f2bf(fmaf(acc[mi][ni][0], sc, bb));
                pk.y = f2bf(fmaf(acc[mi][ni][1], sc, bb));
                pk.z = f2bf(fmaf(acc[mi][ni][2], sc, bb));
                pk.w = f2bf(fmaf(acc[mi][ni][3], sc, bb));
                u16* O = (z == 0) ? qtb : vtb;
                *(ushort4*)(O + ((size_t)(b * NH + h) * HD + d) * SEQ + n0) = pk;
            }
        }
    }
}

// ---------------- output GEMM: fp32 out + bias ----------------
__global__ __launch_bounds__(256, 3) void gemm_out(
    const u16* __restrict__ A, const u16* __restrict__ wo,
    const float* __restrict__ bo, float* __restrict__ Cout)
{
    const int tid = threadIdx.x;
    const int l = tid & 63, w = tid >> 6;
    const int wm = w & 1, wn = w >> 1;
    const int lr = l & 15, lg = l >> 4;
    const int mt = blockIdx.x, nt = blockIdx.y;

    const u16* Ag = A + (size_t)(mt * 128) * HID;
    const u16* Bg = wo + (size_t)(nt * 128) * HID;

    f32x4 acc[4][4] = {};
    gemm_mainloop(Ag, Bg, acc);

#pragma unroll
    for (int mi = 0; mi < 4; mi++) {
#pragma unroll
        for (int ni = 0; ni < 4; ni++) {
            const int jg = nt * 128 + wn * 64 + ni * 16 + lr;
            float bb = bo[jg];
#pragma unroll
            for (int r2 = 0; r2 < 4; r2++) {
                int ig = mt * 128 + wm * 64 + mi * 16 + lg * 4 + r2;
                Cout[(size_t)ig * HID + jg] = acc[mi][ni][r2] + bb;
            }
        }
    }
}

// ---------------- fused flash attention: barrier-free, NO-MAX softmax ----------------
// K and V^T fragments loaded global->VGPR directly (contiguous 16B each).
// Only LDS use is the per-wave P transform (no barrier). LDS 8 KB/block.
__global__ __launch_bounds__(256, 4) void attn_kernel(
    const u16* __restrict__ qtb, const u16* __restrict__ kb, const u16* __restrict__ vtb,
    const u16* __restrict__ ebb, u16* __restrict__ ob)
{
    __shared__ __align__(16) u16 Ps[4][16 * 64];

    const int tid = threadIdx.x;
    const int l = tid & 63, w = tid >> 6;
    const int lr = l & 15, lg = l >> 4;
    const int h = blockIdx.x, qt = blockIdx.y, b = blockIdx.z;
    const int bh = b * NH + h;
    const int qrow0 = qt * 64 + w * 16;

    const u16* Kg = kb + (size_t)bh * SEQ * HD;
    const u16* Vg = vtb + (size_t)bh * HD * SEQ;
    const u16* Eg = ebb + ((size_t)b * SEQ + qrow0 + lg * 4) * SEQ;

    // Q fragments (A-layout) gathered from transposed Q [b,h,d,n]
    const u16* Qg = qtb + (size_t)bh * HD * SEQ + qrow0 + lr;
    bf16x8 qf0, qf1;
#pragma unroll
    for (int j = 0; j < 8; j++) {
        qf0[j] = __builtin_bit_cast(__bf16, Qg[(size_t)(lg * 8 + j) * SEQ]);
        qf1[j] = __builtin_bit_cast(__bf16, Qg[(size_t)(lg * 8 + j + 32) * SEQ]);
    }

    bf16x8 ones;
#pragma unroll
    for (int j = 0; j < 8; j++) ones[j] = __builtin_bit_cast(__bf16, (u16)0x3F80);

    f32x4 oacc[4] = {};
    f32x4 lacc = {};
    float amax[4] = {0.f, 0.f, 0.f, 0.f};

    for (int t = 0; t < 8; t++) {
        const int mt0 = t * 64;

        // bias tile (C-fragment layout) — independent loads, issue early
        u16 bl[4][4];
#pragma unroll
        for (int mi = 0; mi < 4; mi++)
#pragma unroll
            for (int r = 0; r < 4; r++)
                bl[mi][r] = Eg[(size_t)r * SEQ + mt0 + mi * 16 + lr];

        // S = (Q*scale) K^T + bias; K frags direct from global (16B/lane)
        float sm[4][4];
#pragma unroll
        for (int mi = 0; mi < 4; mi++) {
            const u16* Kr = Kg + (size_t)(mt0 + mi * 16 + lr) * HD + lg * 8;
            bf16x8 kf0 = *(const bf16x8*)(Kr);
            bf16x8 kf1 = *(const bf16x8*)(Kr + 32);
            f32x4 s;
#pragma unroll
            for (int r = 0; r < 4; r++) s[r] = bf2f(bl[mi][r]);
            s = __builtin_amdgcn_mfma_f32_16x16x32_bf16(qf0, kf0, s, 0, 0, 0);
            s = __builtin_amdgcn_mfma_f32_16x16x32_bf16(qf1, kf1, s, 0, 0, 0);
#pragma unroll
            for (int r = 0; r < 4; r++) {
                float sv = s[r];
                amax[r] = fmaxf(amax[r], fabsf(sv));
                sm[mi][r] = __expf(sv);
            }
        }

        // P: C-layout -> per-wave swizzled LDS -> A-layout (no barrier needed)
        u16* Pw = Ps[w];
#pragma unroll
        for (int mi = 0; mi < 4; mi++)
#pragma unroll
            for (int r = 0; r < 4; r++) {
                const int q = lg * 4 + r;
                const int chunk = mi * 2 + (lr >> 3);
                Pw[q * 64 + ((chunk ^ (q & 7)) * 8) + (lr & 7)] = f2bf(sm[mi][r]);
            }

#pragma unroll
        for (int ks = 0; ks < 2; ks++) {
            bf16x8 pf = *(const bf16x8*)(Pw + lr * 64 + (((ks * 4 + lg) ^ (lr & 7)) * 8));
#pragma unroll
            for (int di = 0; di < 4; di++) {
                // V^T frag direct from global (16B/lane)
                bf16x8 vf = *(const bf16x8*)(Vg + (size_t)(di * 16 + lr) * SEQ + mt0 + ks * 32 + lg * 8);
                oacc[di] = __builtin_amdgcn_mfma_f32_16x16x32_bf16(pf, vf, oacc[di], 0, 0, 0);
            }
            lacc = __builtin_amdgcn_mfma_f32_16x16x32_bf16(pf, ones, lacc, 0, 0, 0);
        }
    }

#pragma unroll
    for (int r = 0; r < 4; r++) {
        float am = amax[r];
        am = fmaxf(am, __shfl_xor(am, 1));
        am = fmaxf(am, __shfl_xor(am, 2));
        am = fmaxf(am, __shfl_xor(am, 4));
        am = fmaxf(am, __shfl_xor(am, 8));
        float inv = (am > 0.f) ? (1.0f / lacc[r]) : 0.0f;  // all-zero row -> 0 (ref: NaN->0)
        int n = qrow0 + lg * 4 + r;
        u16* orow = ob + ((size_t)b * SEQ + n) * HID + h * HD;
#pragma unroll
        for (int di = 0; di < 4; di++)
            orow[di * 16 + lr] = f2bf(oacc[di][r] * inv);
    }
}

// ---------------- launch ----------------
extern "C" void kernel_launch(void* const* d_in, const int* in_sizes, int n_in,
                              void* d_out, int out_size, void* d_ws, size_t ws_size,
                              hipStream_t stream) {
    (void)in_sizes; (void)n_in; (void)out_size; (void)ws_size;
    const float* x  = (const float*)d_in[0];
    const float* eb = (const float*)d_in[1];
    const float* Wq = (const float*)d_in[2];
    const float* Wk = (const float*)d_in[3];
    const float* Wv = (const float*)d_in[4];
    const float* bv = (const float*)d_in[5];
    const float* Wo = (const float*)d_in[6];
    const float* bo = (const float*)d_in[7];
    float* out = (float*)d_out;

    const int NX = BATCH * SEQ * HID;   // 6291456
    const int NW = HID * HID;           // 589824
    const int NE = BATCH * SEQ * SEQ;   // 4194304
    u16* ws   = (u16*)d_ws;
    u16* xb   = ws;                 // contiguous cvt region: [x | eb | wq | wk | wv | wo]
    u16* ebb  = xb + NX;
    u16* wqb  = ebb + NE;
    u16* wkb  = wqb + NW;
    u16* wvb  = wkb + NW;
    u16* wob  = wvb + NW;
    u16* qtb  = wob + NW;
    u16* kb   = qtb + NX;
    u16* vtb  = kb + NX;
    u16* obuf = vtb + NX;

    cvt_all<<<NXB + NEB + 4 * NWB, 256, 0, stream>>>(x, eb, Wq, Wk, Wv, Wo, ws);

    gemm_qkv<<<dim3(64, 6, 3), 256, 0, stream>>>(xb, wqb, wkb, wvb, bv, qtb, kb, vtb);

    attn_kernel<<<dim3(NH, 8, BATCH), 256, 0, stream>>>(qtb, kb, vtb, ebb, obuf);

    gemm_out<<<dim3(64, 6), 256, 0, stream>>>(obuf, wob, bo, out);
}

// Round 8
// 206.536 us; speedup vs baseline: 1.7274x; 1.7274x over previous
//
#include <hip/hip_runtime.h>
#include <stdint.h>

typedef unsigned short u16;
typedef unsigned int u32;
typedef __bf16 bf16x8 __attribute__((ext_vector_type(8)));
typedef float f32x4 __attribute__((ext_vector_type(4)));

#define NH 12
#define HD 64
#define SEQ 512
#define BATCH 16
#define HID 768
#define SCALE_Q 0.03608439182435161f  // 768^-0.5

__device__ __forceinline__ u16 f2bf(float f) {
    u32 u = __builtin_bit_cast(u32, f);
    u32 r = (u + 0x7FFFu + ((u >> 16) & 1u)) >> 16;
    return (u16)r;
}
__device__ __forceinline__ float bf2f(u16 h) {
    return __builtin_bit_cast(float, (u32)h << 16);
}

// async global -> LDS, 16B per lane; lds dest = wave-uniform base + lane*16
__device__ __forceinline__ void gl2lds16(const u16* g, u16* lds_base) {
    __builtin_amdgcn_global_load_lds(
        (const __attribute__((address_space(1))) u32*)g,
        (__attribute__((address_space(3))) u32*)lds_base, 16, 0, 0);
}

// ---------------- fused fp32 -> bf16 convert (all 6 tensors, one launch) ----------------
#define NXB 6144   // NX/1024
#define NEB 4096   // NE/1024
#define NWB 576    // NW/1024
__global__ void cvt_all(const float* __restrict__ x, const float* __restrict__ eb,
                        const float* __restrict__ w0, const float* __restrict__ w1,
                        const float* __restrict__ w2, const float* __restrict__ w3,
                        u16* __restrict__ dst) {
    int b = blockIdx.x;
    const float* s; int sb;
    if (b < NXB) { s = x; sb = 0; }
    else if (b < NXB + NEB) { s = eb; sb = NXB; }
    else if (b < NXB + NEB + NWB) { s = w0; sb = NXB + NEB; }
    else if (b < NXB + NEB + 2 * NWB) { s = w1; sb = NXB + NEB + NWB; }
    else if (b < NXB + NEB + 3 * NWB) { s = w2; sb = NXB + NEB + 2 * NWB; }
    else { s = w3; sb = NXB + NEB + 3 * NWB; }
    int li = (b - sb) * 1024 + threadIdx.x * 4;
    float4 v = *(const float4*)(s + li);
    ushort4 o;
    o.x = f2bf(v.x); o.y = f2bf(v.y); o.z = f2bf(v.z); o.w = f2bf(v.w);
    *(ushort4*)(dst + (size_t)b * 1024 + threadIdx.x * 4) = o;
}

// ---------------- double-buffered NT GEMM mainloop, row-major LDS + XOR swizzle ----------------
// LDS tile [128 rows][32 cols]; row's four 16B chunks stored at slot = c ^ ((row>>1)&3).
// Staging: 4 lanes/row read the SAME 64B row span (coalescing unchanged vs R4);
// frag reads: 16 lanes spread over 4 slots x 2 bank-halves = 2-way = free (m136).
__device__ __forceinline__ void stage_gemm(
    const u16* __restrict__ Ag, const u16* __restrict__ Bg, int k0,
    u16* As, u16* Bs, int r0, int q0, int r1, int q1, int w)
{
    gl2lds16(Ag + (size_t)r0 * HID + k0 + q0, As + w * 512);
    gl2lds16(Ag + (size_t)r1 * HID + k0 + q1, As + 2048 + w * 512);
    gl2lds16(Bg + (size_t)r0 * HID + k0 + q0, Bs + w * 512);
    gl2lds16(Bg + (size_t)r1 * HID + k0 + q1, Bs + 2048 + w * 512);
}

__device__ __forceinline__ void gemm_mainloop(
    const u16* __restrict__ Ag, const u16* __restrict__ Bg,
    u16 (*As)[128 * 32], u16 (*Bs)[128 * 32], f32x4 (&acc)[4][4])
{
    const int tid = threadIdx.x;
    const int l = tid & 63, w = tid >> 6;
    const int wm = w & 1, wn = w >> 1;
    const int lr = l & 15, lg = l >> 4;

    // staging: thread handles LDS slot (row=c>>2, s=c&3); fetches chunk s^((row>>1)&3)
    const int c0 = tid, c1 = tid + 256;
    const int r0 = c0 >> 2, q0 = (((c0 & 3) ^ ((r0 >> 1) & 3)) * 8);
    const int r1 = c1 >> 2, q1 = (((c1 & 3) ^ ((r1 >> 1) & 3)) * 8);

    // frag-read col slot for data chunk lg at row base+lr: lg ^ ((lr>>1)&3)
    const int sA = (lg ^ ((lr >> 1) & 3)) * 8;

    stage_gemm(Ag, Bg, 0, As[0], Bs[0], r0, q0, r1, q1, w);

    for (int i = 0; i < 24; i++) {
        const int cur = i & 1;
        __syncthreads();  // drains tile-i loads; prev reads done
        if (i < 23)
            stage_gemm(Ag, Bg, (i + 1) * 32, As[cur ^ 1], Bs[cur ^ 1], r0, q0, r1, q1, w);

        bf16x8 af[4], bfr[4];
#pragma unroll
        for (int mi = 0; mi < 4; mi++)
            af[mi] = *(const bf16x8*)(As[cur] + (wm * 64 + mi * 16 + lr) * 32 + sA);
#pragma unroll
        for (int ni = 0; ni < 4; ni++)
            bfr[ni] = *(const bf16x8*)(Bs[cur] + (wn * 64 + ni * 16 + lr) * 32 + sA);
#pragma unroll
        for (int mi = 0; mi < 4; mi++)
#pragma unroll
            for (int ni = 0; ni < 4; ni++)
                acc[mi][ni] = __builtin_amdgcn_mfma_f32_16x16x32_bf16(af[mi], bfr[ni], acc[mi][ni], 0, 0, 0);
    }
}

// ---------------- fused QKV GEMM ----------------
__global__ __launch_bounds__(256, 4) void gemm_qkv(
    const u16* __restrict__ xb, const u16* __restrict__ wq,
    const u16* __restrict__ wk, const u16* __restrict__ wv,
    const float* __restrict__ bv,
    u16* __restrict__ qtb, u16* __restrict__ kb, u16* __restrict__ vtb)
{
    __shared__ __align__(16) u16 As[2][128 * 32];
    __shared__ __align__(16) u16 Bs[2][128 * 32];
    const int tid = threadIdx.x;
    const int l = tid & 63, w = tid >> 6;
    const int wm = w & 1, wn = w >> 1;
    const int lr = l & 15, lg = l >> 4;
    const int mt = blockIdx.x, nt = blockIdx.y, z = blockIdx.z;

    const u16* Bw = (z == 0) ? wq : (z == 1) ? wk : wv;
    const u16* Ag = xb + (size_t)(mt * 128) * HID;
    const u16* Bg = Bw + (size_t)(nt * 128) * HID;

    f32x4 acc[4][4] = {};
    gemm_mainloop(Ag, Bg, As, Bs, acc);

    const float sc = (z == 0) ? SCALE_Q : 1.0f;
#pragma unroll
    for (int mi = 0; mi < 4; mi++) {
#pragma unroll
        for (int ni = 0; ni < 4; ni++) {
            const int jg = nt * 128 + wn * 64 + ni * 16 + lr;
            const int h = jg >> 6, d = jg & 63;
            const int i0 = mt * 128 + wm * 64 + mi * 16 + lg * 4;
            const int b = i0 >> 9, n0 = i0 & 511;
            if (z == 1) {  // K: [b,h,m,d]
#pragma unroll
                for (int r2 = 0; r2 < 4; r2++)
                    kb[((size_t)(b * NH + h) * SEQ + n0 + r2) * HD + d] = f2bf(acc[mi][ni][r2]);
            } else {       // Q/V: [b,h,d,n] packed along n
                float bb = (z == 2) ? bv[jg] : 0.0f;
                ushort4 pk;
                pk.x = f2bf(fmaf(acc[mi][ni][0], sc, bb));
                pk.y = f2bf(fmaf(acc[mi][ni][1], sc, bb));
                pk.z = f2bf(fmaf(acc[mi][ni][2], sc, bb));
                pk.w = f2bf(fmaf(acc[mi][ni][3], sc, bb));
                u16* O = (z == 0) ? qtb : vtb;
                *(ushort4*)(O + ((size_t)(b * NH + h) * HD + d) * SEQ + n0) = pk;
            }
        }
    }
}

// ---------------- output GEMM: fp32 out + bias ----------------
__global__ __launch_bounds__(256, 4) void gemm_out(
    const u16* __restrict__ A, const u16* __restrict__ wo,
    const float* __restrict__ bo, float* __restrict__ Cout)
{
    __shared__ __align__(16) u16 As[2][128 * 32];
    __shared__ __align__(16) u16 Bs[2][128 * 32];
    const int tid = threadIdx.x;
    const int l = tid & 63, w = tid >> 6;
    const int wm = w & 1, wn = w >> 1;
    const int lr = l & 15, lg = l >> 4;
    const int mt = blockIdx.x, nt = blockIdx.y;

    const u16* Ag = A + (size_t)(mt * 128) * HID;
    const u16* Bg = wo + (size_t)(nt * 128) * HID;

    f32x4 acc[4][4] = {};
    gemm_mainloop(Ag, Bg, As, Bs, acc);

#pragma unroll
    for (int mi = 0; mi < 4; mi++) {
#pragma unroll
        for (int ni = 0; ni < 4; ni++) {
            const int jg = nt * 128 + wn * 64 + ni * 16 + lr;
            float bb = bo[jg];
#pragma unroll
            for (int r2 = 0; r2 < 4; r2++) {
                int ig = mt * 128 + wm * 64 + mi * 16 + lg * 4 + r2;
                Cout[(size_t)ig * HID + jg] = acc[mi][ni][r2] + bb;
            }
        }
    }
}

// ---------------- fused flash attention, NO-MAX softmax (Round-5-bench version) ----------------
__device__ __forceinline__ void stage_kv(
    const u16* __restrict__ Kg, const u16* __restrict__ Vg, int mt0,
    u16* Ksb, u16* Vsb, int kr0, int kc0, int kr1, int kc1, int w)
{
    gl2lds16(Kg + (size_t)(mt0 + kr0) * HD + kc0 * 8, Ksb + w * 512);
    gl2lds16(Kg + (size_t)(mt0 + kr1) * HD + kc1 * 8, Ksb + 2048 + w * 512);
    gl2lds16(Vg + (size_t)kr0 * SEQ + mt0 + kc0 * 8, Vsb + w * 512);
    gl2lds16(Vg + (size_t)kr1 * SEQ + mt0 + kc1 * 8, Vsb + 2048 + w * 512);
}

__global__ __launch_bounds__(256, 4) void attn_kernel(
    const u16* __restrict__ qtb, const u16* __restrict__ kb, const u16* __restrict__ vtb,
    const u16* __restrict__ ebb, u16* __restrict__ ob)
{
    __shared__ __align__(16) u16 Ks[2][64 * 64];
    __shared__ __align__(16) u16 Vs[2][64 * 64];
    __shared__ __align__(16) u16 Ps[4][16 * 64];

    const int tid = threadIdx.x;
    const int l = tid & 63, w = tid >> 6;
    const int lr = l & 15, lg = l >> 4;
    const int h = blockIdx.x, qt = blockIdx.y, b = blockIdx.z;
    const int bh = b * NH + h;
    const int qrow0 = qt * 64 + w * 16;

    const u16* Kg = kb + (size_t)bh * SEQ * HD;
    const u16* Vg = vtb + (size_t)bh * HD * SEQ;
    const u16* Eg = ebb + ((size_t)b * SEQ + qrow0 + lg * 4) * SEQ;

    // staging chunk assignment (swizzled): p = row*8 + (c ^ (row&7))
    const int p0 = tid, p1 = tid + 256;
    const int kr0 = p0 >> 3, kc0 = (p0 & 7) ^ (kr0 & 7);
    const int kr1 = p1 >> 3, kc1 = (p1 & 7) ^ (kr1 & 7);

    stage_kv(Kg, Vg, 0, Ks[0], Vs[0], kr0, kc0, kr1, kc1, w);

    // Q fragments (A-layout) gathered from transposed Q [b,h,d,n]
    const u16* Qg = qtb + (size_t)bh * HD * SEQ + qrow0 + lr;
    bf16x8 qf0, qf1;
#pragma unroll
    for (int j = 0; j < 8; j++) {
        qf0[j] = __builtin_bit_cast(__bf16, Qg[(size_t)(lg * 8 + j) * SEQ]);
        qf1[j] = __builtin_bit_cast(__bf16, Qg[(size_t)(lg * 8 + j + 32) * SEQ]);
    }

    bf16x8 ones;
#pragma unroll
    for (int j = 0; j < 8; j++) ones[j] = __builtin_bit_cast(__bf16, (u16)0x3F80);

    f32x4 oacc[4] = {};
    f32x4 lacc = {};
    float amax[4] = {0.f, 0.f, 0.f, 0.f};

    for (int t = 0; t < 8; t++) {
        const int cur = t & 1;
        const int mt0 = t * 64;
        __syncthreads();  // drains tile-t loads; prev tile's reads done

        // bias loads FIRST (vmcnt-ordered before the prefetch below)
        u16 bl[4][4];
#pragma unroll
        for (int mi = 0; mi < 4; mi++)
#pragma unroll
            for (int r = 0; r < 4; r++)
                bl[mi][r] = Eg[(size_t)r * SEQ + mt0 + mi * 16 + lr];

        if (t < 7)
            stage_kv(Kg, Vg, mt0 + 64, Ks[cur ^ 1], Vs[cur ^ 1], kr0, kc0, kr1, kc1, w);

        // S = (Q*scale) K^T + bias (bias as MFMA C-init); P = exp(S), no max
        float sm[4][4];
#pragma unroll
        for (int mi = 0; mi < 4; mi++) {
            const int row = mi * 16 + lr;
            bf16x8 kf0 = *(const bf16x8*)(Ks[cur] + row * 64 + ((lg ^ (row & 7)) * 8));
            bf16x8 kf1 = *(const bf16x8*)(Ks[cur] + row * 64 + (((4 + lg) ^ (row & 7)) * 8));
            f32x4 s;
#pragma unroll
            for (int r = 0; r < 4; r++) s[r] = bf2f(bl[mi][r]);
            s = __builtin_amdgcn_mfma_f32_16x16x32_bf16(qf0, kf0, s, 0, 0, 0);
            s = __builtin_amdgcn_mfma_f32_16x16x32_bf16(qf1, kf1, s, 0, 0, 0);
#pragma unroll
            for (int r = 0; r < 4; r++) {
                float sv = s[r];
                amax[r] = fmaxf(amax[r], fabsf(sv));
                sm[mi][r] = __expf(sv);
            }
        }

        // P: C-layout -> per-wave swizzled LDS -> A-layout
        u16* Pw = Ps[w];
#pragma unroll
        for (int mi = 0; mi < 4; mi++)
#pragma unroll
            for (int r = 0; r < 4; r++) {
                const int q = lg * 4 + r;
                const int chunk = mi * 2 + (lr >> 3);
                Pw[q * 64 + ((chunk ^ (q & 7)) * 8) + (lr & 7)] = f2bf(sm[mi][r]);
            }

#pragma unroll
        for (int ks = 0; ks < 2; ks++) {
            bf16x8 pf = *(const bf16x8*)(Pw + lr * 64 + (((ks * 4 + lg) ^ (lr & 7)) * 8));
#pragma unroll
            for (int di = 0; di < 4; di++) {
                const int row = di * 16 + lr;
                bf16x8 vf = *(const bf16x8*)(Vs[cur] + row * 64 + (((ks * 4 + lg) ^ (row & 7)) * 8));
                oacc[di] = __builtin_amdgcn_mfma_f32_16x16x32_bf16(pf, vf, oacc[di], 0, 0, 0);
            }
            lacc = __builtin_amdgcn_mfma_f32_16x16x32_bf16(pf, ones, lacc, 0, 0, 0);
        }
    }

#pragma unroll
    for (int r = 0; r < 4; r++) {
        float am = amax[r];
        am = fmaxf(am, __shfl_xor(am, 1));
        am = fmaxf(am, __shfl_xor(am, 2));
        am = fmaxf(am, __shfl_xor(am, 4));
        am = fmaxf(am, __shfl_xor(am, 8));
        float inv = (am > 0.f) ? (1.0f / lacc[r]) : 0.0f;  // all-zero row -> 0 (ref: NaN->0)
        int n = qrow0 + lg * 4 + r;
        u16* orow = ob + ((size_t)b * SEQ + n) * HID + h * HD;
#pragma unroll
        for (int di = 0; di < 4; di++)
            orow[di * 16 + lr] = f2bf(oacc[di][r] * inv);
    }
}

// ---------------- launch ----------------
extern "C" void kernel_launch(void* const* d_in, const int* in_sizes, int n_in,
                              void* d_out, int out_size, void* d_ws, size_t ws_size,
                              hipStream_t stream) {
    (void)in_sizes; (void)n_in; (void)out_size; (void)ws_size;
    const float* x  = (const float*)d_in[0];
    const float* eb = (const float*)d_in[1];
    const float* Wq = (const float*)d_in[2];
    const float* Wk = (const float*)d_in[3];
    const float* Wv = (const float*)d_in[4];
    const float* bv = (const float*)d_in[5];
    const float* Wo = (const float*)d_in[6];
    const float* bo = (const float*)d_in[7];
    float* out = (float*)d_out;

    const int NX = BATCH * SEQ * HID;   // 6291456
    const int NW = HID * HID;           // 589824
    const int NE = BATCH * SEQ * SEQ;   // 4194304
    u16* ws   = (u16*)d_ws;
    u16* xb   = ws;                 // contiguous cvt region: [x | eb | wq | wk | wv | wo]
    u16* ebb  = xb + NX;
    u16* wqb  = ebb + NE;
    u16* wkb  = wqb + NW;
    u16* wvb  = wkb + NW;
    u16* wob  = wvb + NW;
    u16* qtb  = wob + NW;
    u16* kb   = qtb + NX;
    u16* vtb  = kb + NX;
    u16* obuf = vtb + NX;

    cvt_all<<<NXB + NEB + 4 * NWB, 256, 0, stream>>>(x, eb, Wq, Wk, Wv, Wo, ws);

    gemm_qkv<<<dim3(64, 6, 3), 256, 0, stream>>>(xb, wqb, wkb, wvb, bv, qtb, kb, vtb);

    attn_kernel<<<dim3(NH, 8, BATCH), 256, 0, stream>>>(qtb, kb, vtb, ebb, obuf);

    gemm_out<<<dim3(64, 6), 256, 0, stream>>>(obuf, wob, bo, out);
}